// Round 17
// baseline (111.785 us; speedup 1.0000x reference)
//
#include <hip/hip_runtime.h>
#include <hip/hip_bf16.h>

typedef unsigned short u16;
typedef unsigned int u32;
typedef u16 u16x4 __attribute__((ext_vector_type(4)));
typedef u16 u16x8 __attribute__((ext_vector_type(8)));
typedef u32 u32x4 __attribute__((ext_vector_type(4)));
typedef __bf16 bf16x8 __attribute__((ext_vector_type(8)));
typedef float f32x4 __attribute__((ext_vector_type(4)));

__device__ __forceinline__ u16 f2bf(float f) {
  union { float f; unsigned u; } v; v.f = f;
  unsigned r = v.u + 0x7fffu + ((v.u >> 16) & 1u);
  return (u16)(r >> 16);
}

__device__ __forceinline__ u16 bf(float f) {
  __bf16 h = (__bf16)f;
  union { __bf16 h; u16 u; } c; c.h = h;
  return c.u;
}

__device__ __forceinline__ u32 pack2(float lo, float hi) {
  return (u32)bf(lo) | ((u32)bf(hi) << 16);
}

__device__ __forceinline__ float fexp2(float x) {
#if __has_builtin(__builtin_amdgcn_exp2f)
  return __builtin_amdgcn_exp2f(x);
#else
  return exp2f(x);
#endif
}

__device__ __forceinline__ float frcp(float x) {
#if __has_builtin(__builtin_amdgcn_rcpf)
  return __builtin_amdgcn_rcpf(x);
#else
  return 1.0f / x;
#endif
}

__device__ __forceinline__ void gload16(const void* g, void* l) {
  __builtin_amdgcn_global_load_lds((const __attribute__((address_space(1))) void*)g,
                                   (__attribute__((address_space(3))) void*)l, 16, 0, 0);
}

// ---- merged prep: x f32->bf16 (blocks 0..2047) + weight transposes (2048..6143)
__global__ __launch_bounds__(256) void prep(
    const float* __restrict__ x, const float* __restrict__ Wqkv,
    const float* __restrict__ Wproj, u16* __restrict__ xb,
    u16* __restrict__ wqT, u16* __restrict__ wpT)
{
  __shared__ float tile[32][33];
  const int bid = blockIdx.x;
  if (bid < 2048) {
    int i = (bid * 256 + threadIdx.x) * 8;
    f32x4 a = *(const f32x4*)(x + i);
    f32x4 b = *(const f32x4*)(x + i + 4);
    u16x8 r;
    r[0] = f2bf(a[0]); r[1] = f2bf(a[1]); r[2] = f2bf(a[2]); r[3] = f2bf(a[3]);
    r[4] = f2bf(b[0]); r[5] = f2bf(b[1]); r[6] = f2bf(b[2]); r[7] = f2bf(b[3]);
    *(u16x8*)(xb + i) = r;
    return;
  }
  int flat = bid - 2048;
  int bx = flat & 127, by = flat >> 7;
  const float* in;
  u16* out;
  int N;
  if (bx < 96) { in = Wqkv; out = wqT; N = 3072; }
  else         { in = Wproj; out = wpT; N = 1024; bx -= 96; }
  const int K = 1024;
  int n0 = bx * 32, k0 = by * 32;
  int tx = threadIdx.x & 31, ty = threadIdx.x >> 5;
  for (int i = 0; i < 32; i += 8)
    tile[ty + i][tx] = in[(long)(k0 + ty + i) * N + n0 + tx];
  __syncthreads();
  for (int i = 0; i < 32; i += 8)
    out[(long)(n0 + ty + i) * K + k0 + tx] = f2bf(tile[tx][ty + i]);
}

// ------------- GEMM: C[M][N] = A[M][K] * Bt[N][K]^T (+bias), BK=64 -------------
template<int BM, int BN, bool F32OUT>
__global__ __launch_bounds__(256) void gemm_bt(
    const u16* __restrict__ A, const u16* __restrict__ Bt,
    void* __restrict__ Cp, const float* __restrict__ bias,
    int M, int N, int K)
{
  constexpr int MR = BM / 32, NR = BN / 32;
  constexpr int RA = BM / 32, RB = BN / 32;
  __shared__ char lds[(BM + BN) * 128];
  char* As = lds;
  char* Bs = lds + BM * 128;
  const int tid = threadIdx.x;
  const int l = tid & 63, w = tid >> 6;
  const int wr = w >> 1, wc = w & 1;
  const int lr = l & 15, q4 = l >> 4;
  const long row0 = (long)blockIdx.x * BM;
  const long col0 = (long)blockIdx.y * BN;

  f32x4 acc[MR][NR] = {};

  const u16* gA[RA];
  int oA[RA];
  for (int i = 0; i < RA; ++i) {
    int cc = i * 256 + tid;
    int r = cc >> 3, c = (cc & 7) ^ (r & 7);
    oA[i] = cc * 16;
    gA[i] = A + (row0 + r) * K + c * 8;
  }
  const u16* gB[RB];
  int oB[RB];
  for (int i = 0; i < RB; ++i) {
    int cc = i * 256 + tid;
    int r = cc >> 3, c = (cc & 7) ^ (r & 7);
    oB[i] = cc * 16;
    gB[i] = Bt + (col0 + r) * K + c * 8;
  }

  for (int k0 = 0; k0 < K; k0 += 64) {
    __syncthreads();
    for (int i = 0; i < RA; ++i) gload16(gA[i] + k0, As + oA[i]);
    for (int i = 0; i < RB; ++i) gload16(gB[i] + k0, Bs + oB[i]);
    __syncthreads();
    for (int kk = 0; kk < 2; ++kk) {
      bf16x8 a[MR], b[NR];
      for (int m = 0; m < MR; ++m) {
        int r = wr * (BM / 2) + m * 16 + lr;
        a[m] = *(const bf16x8*)(As + r * 128 + (((kk * 4 + q4) ^ (r & 7)) << 4));
      }
      for (int n = 0; n < NR; ++n) {
        int r = wc * (BN / 2) + n * 16 + lr;
        b[n] = *(const bf16x8*)(Bs + r * 128 + (((kk * 4 + q4) ^ (r & 7)) << 4));
      }
      for (int m = 0; m < MR; ++m)
        for (int n = 0; n < NR; ++n)
          acc[m][n] = __builtin_amdgcn_mfma_f32_16x16x32_bf16(a[m], b[n], acc[m][n], 0, 0, 0);
    }
  }

  for (int n = 0; n < NR; ++n) {
    int col = (int)col0 + wc * (BN / 2) + n * 16 + lr;
    float bv = 0.f;
    if (F32OUT) bv = bias[col];
    for (int m = 0; m < MR; ++m) {
      for (int reg = 0; reg < 4; ++reg) {
        long row = row0 + wr * (BM / 2) + m * 16 + q4 * 4 + reg;
        float vv = acc[m][n][reg] + bv;
        if (F32OUT) ((float*)Cp)[row * N + col] = vv;
        else        ((u16*)Cp)[row * N + col] = f2bf(vv);
      }
    }
  }
}

// ------------- causal flash attention (uniform 17-iter split-K schedule) ----
// 512 thr, 8 waves. Block = pair {64-row tile ti, 64-row tile 31-ti}.
// Waves 4-7 (B): hi-tile rows, KV tiles 0..15 (16 tiles).
// Waves 0-3 (A): lo-tile rows for KV tiles 0..ti, THEN hi-row PARTIALS for
// KV tiles 16..31-ti (17 tiles total). Every wave busy every iteration;
// every block runs exactly 17 iterations -> no imbalance anywhere.
// Fixed-reference softmax (P = exp2(st), no running max) makes the split-K
// combine a plain add of O and lsum (one LDS pass in the epilogue).
// Slots: B-stream -> {2,3}; A-stream own tiles -> {0,1}; shared early tiles
// (lo's KV range is a subset of hi's) read from B's slots -> staged bytes
// identical to the sequential schedule. Depth-1 prefetch, barrier per iter.
// V column permutation: key = n*16+g*4+r -> col' = (n>>1)*32+g*8+(n&1)*4+r
#define FXOR(d) (((((d) & 7) ^ (((d) >> 3) & 7))) << 4)

#define VSCAT(vtb, ra, rb)                                                     \
  for (int j = 0; j < 4; ++j) {                                                \
    int d = vd0 + j;                                                           \
    *(u32*)((vtb) + d * 128 + (vcol2 ^ FXOR(d))) = (u32)(ra)[j] | ((u32)(rb)[j] << 16); \
  }

#define CTILE(QF, OACC, LS, SLOT, K0, ROW, DOMASK)                             \
  {                                                                            \
    char* ks_ = ksmem + (SLOT) * 8192;                                         \
    char* vt_ = vtmem + (SLOT) * 8192;                                         \
    f32x4 st[4] = {};                                                          \
    __builtin_amdgcn_s_setprio(1);                                             \
    for (int kk = 0; kk < 2; ++kk)                                             \
      for (int n = 0; n < 4; ++n) {                                            \
        int r = n * 16 + lr;                                                   \
        int c = (kk * 4 + g) ^ (r & 7);                                        \
        bf16x8 kf = *(const bf16x8*)(ks_ + r * 128 + (c << 4));                \
        st[n] = __builtin_amdgcn_mfma_f32_16x16x32_bf16(kf, QF[kk], st[n], 0, 0, 0); \
      }                                                                        \
    __builtin_amdgcn_s_setprio(0);                                             \
    if (DOMASK) {                                                              \
      for (int n = 0; n < 4; ++n)                                              \
        for (int reg = 0; reg < 4; ++reg)                                      \
          if ((K0) + n * 16 + g * 4 + reg > (ROW) + lr)                        \
            st[n][reg] = -__builtin_inff();                                    \
    }                                                                          \
    float psum = 0.f;                                                          \
    u32 pk[4][2];                                                              \
    for (int n = 0; n < 4; ++n) {                                              \
      float p0 = fexp2(st[n][0]), p1 = fexp2(st[n][1]);                        \
      float p2 = fexp2(st[n][2]), p3 = fexp2(st[n][3]);                        \
      psum += (p0 + p1) + (p2 + p3);                                           \
      pk[n][0] = pack2(p0, p1);                                                \
      pk[n][1] = pack2(p2, p3);                                                \
    }                                                                          \
    LS += psum;                                                                \
    __builtin_amdgcn_s_setprio(1);                                             \
    for (int kt = 0; kt < 2; ++kt) {                                           \
      u32x4 pb;                                                                \
      pb[0] = pk[2 * kt][0]; pb[1] = pk[2 * kt][1];                            \
      pb[2] = pk[2 * kt + 1][0]; pb[3] = pk[2 * kt + 1][1];                    \
      bf16x8 pf = *(bf16x8*)&pb;                                               \
      for (int n = 0; n < 4; ++n) {                                            \
        int dd = n * 16 + lr;                                                  \
        bf16x8 vf = *(const bf16x8*)(vt_ + dd * 128 + ((kt * 64 + g * 16) ^ FXOR(dd))); \
        OACC[n] = __builtin_amdgcn_mfma_f32_16x16x32_bf16(vf, pf, OACC[n], 0, 0, 0); \
      }                                                                        \
    }                                                                          \
    __builtin_amdgcn_s_setprio(0);                                             \
  }

__global__ __launch_bounds__(512) void attn_fwd(
    const u16* __restrict__ qkv, u16* __restrict__ atty)
{
  __shared__ char ksmem[4 * 8192];      // K slots: 0,1 = A-stream; 2,3 = B-stream
  __shared__ char vtmem[4 * 8192];      // V slots (key-permuted, swizzled)
  const int tid = threadIdx.x;
  const int l = tid & 63, w = tid >> 6;
  const int lr = l & 15, g = l >> 4;
  const int h = blockIdx.y;
  const int ti = blockIdx.x;            // 0..15
  const long base = (long)blockIdx.z * 2048;
  const bool isA = w < 4;
  const int wq = w & 3;
  const int lorow = ti * 64 + wq * 16;
  const int hirow = (31 - ti) * 64 + wq * 16;

  // Q fragments, pre-scaled by 0.125*log2(e). All waves load hi-row frag
  // (B computes hi rows; A computes hi-row partials); A also loads lo-row.
  bf16x8 qfH[2], qfL[2];
  for (int kk = 0; kk < 2; ++kk) {
    u16x8 raw = *(const u16x8*)(qkv + (base + hirow + lr) * 3072 + h * 64 + kk * 32 + g * 8);
    u16x8 sc;
    for (int j = 0; j < 8; ++j) {
      union { unsigned u; float f; } c; c.u = ((unsigned)raw[j]) << 16;
      sc[j] = bf(c.f * 0.18033688f);
    }
    qfH[kk] = *(bf16x8*)&sc;
  }
  if (isA) {
    for (int kk = 0; kk < 2; ++kk) {
      u16x8 raw = *(const u16x8*)(qkv + (base + lorow + lr) * 3072 + h * 64 + kk * 32 + g * 8);
      u16x8 sc;
      for (int j = 0; j < 8; ++j) {
        union { unsigned u; float f; } c; c.u = ((unsigned)raw[j]) << 16;
        sc[j] = bf(c.f * 0.18033688f);
      }
      qfL[kk] = *(bf16x8*)&sc;
    }
  }

  float ls_hi = 0.f, ls_lo = 0.f;
  f32x4 o_hi[4] = {}, o_lo[4] = {};     // B: o_hi = full hi; A: o_hi = hi partial

  // K staging: one 16B global_load_lds per thread per tile
  const int kr = tid >> 3, kc = (tid & 7) ^ (kr & 7);
  const u16* kg = qkv + (base + kr) * 3072 + 1024 + h * 64 + kc * 8;
  // V staging: all 512 threads; key-pair (2a,2a+1) x 4 d's; u32 writes
  const int va = tid >> 4;
  const int vd0 = (tid & 15) * 4;
  const int vk0 = va * 2;
  const int vn = vk0 >> 4, vgp2 = (vk0 >> 2) & 3, vr = vk0 & 3;
  const int vcol2 = ((vn >> 1) * 32 + vgp2 * 8 + (vn & 1) * 4 + vr) * 2;
  const u16* vgp = qkv + (base + vk0) * 3072 + 2048 + h * 64 + vd0;

  // prologue: stage KV tile 0 into B-slot 2
  {
    u16x4 a0 = *(const u16x4*)(vgp);
    u16x4 b0 = *(const u16x4*)(vgp + 3072);
    gload16(kg, ksmem + 2 * 8192 + tid * 16);
    VSCAT(vtmem + 2 * 8192, a0, b0);
  }
  __syncthreads();

  for (int u = 0; u <= 16; ++u) {
    // prefetch for iteration u+1
    const bool stB = (u + 1) <= 15;                       // B tile u+1
    const bool stA = ((u + 1) > ti) && ((u + 1) <= 16);   // A tile u+16-ti
    const int sB = 2 + ((u + 1) & 1);
    const int sA = (u + 1) & 1;
    u16x4 bva, bvb, ava, avb;
    if (stB) {
      long off = (long)(u + 1) * 196608;
      bva = *(const u16x4*)(vgp + off);
      bvb = *(const u16x4*)(vgp + off + 3072);
      gload16(kg + off, ksmem + sB * 8192 + tid * 16);
    }
    if (stA) {
      long off = (long)(u + 16 - ti) * 196608;
      ava = *(const u16x4*)(vgp + off);
      avb = *(const u16x4*)(vgp + off + 3072);
      gload16(kg + off, ksmem + sA * 8192 + tid * 16);
    }

    // compute
    if (isA) {
      if (u <= ti) {
        CTILE(qfL, o_lo, ls_lo, 2 + (u & 1), 64 * u, lorow, u == ti);
      } else {
        CTILE(qfH, o_hi, ls_hi, u & 1, 64 * (u + 15 - ti), hirow, u == 16);
      }
    } else if (u <= 15) {
      CTILE(qfH, o_hi, ls_hi, 2 + (u & 1), 64 * u, hirow, false);
    }

    // publish prefetched V; barrier drains K DMA + orders scatter
    if (stB) VSCAT(vtmem + sB * 8192, bva, bvb);
    if (stA) VSCAT(vtmem + sA * 8192, ava, avb);
    __syncthreads();
  }

  // combine: A's hi-row partials -> B via LDS (plain add: fixed-ref softmax)
  float* sh = (float*)ksmem;
  const int bofs = (wq * 64 + l) * 17;
  if (isA) {
    for (int n = 0; n < 4; ++n)
      for (int r = 0; r < 4; ++r) sh[bofs + n * 4 + r] = o_hi[n][r];
    sh[bofs + 16] = ls_hi;
  }
  __syncthreads();
  long row;
  if (isA) {
    row = base + lorow + lr;
  } else {
    for (int n = 0; n < 4; ++n)
      for (int r = 0; r < 4; ++r) o_lo[n][r] = o_hi[n][r] + sh[bofs + n * 4 + r];
    ls_lo = ls_hi + sh[bofs + 16];
    row = base + hirow + lr;
  }
  ls_lo += __shfl_xor(ls_lo, 16);
  ls_lo += __shfl_xor(ls_lo, 32);
  float inv = frcp(ls_lo);
  for (int n = 0; n < 4; ++n) {
    u16x4 ov;
    for (int reg = 0; reg < 4; ++reg) ov[reg] = bf(o_lo[n][reg] * inv);
    *(u16x4*)(atty + row * 1024 + h * 64 + n * 16 + g * 4) = ov;
  }
}

extern "C" void kernel_launch(void* const* d_in, const int* in_sizes, int n_in,
                              void* d_out, int out_size, void* d_ws, size_t ws_size,
                              hipStream_t stream) {
  const float* x     = (const float*)d_in[0];
  const float* Wqkv  = (const float*)d_in[1];
  const float* Wproj = (const float*)d_in[2];
  const float* bproj = (const float*)d_in[3];
  char* ws = (char*)d_ws;
  u16* xb   = (u16*)(ws);                    // 4096*1024 bf16      (8 MB)
  u16* wqT  = (u16*)(ws + 8388608);          // [3072][1024] bf16   (6 MB)
  u16* wpT  = (u16*)(ws + 14680064);         // [1024][1024] bf16   (2 MB)
  u16* qkv  = (u16*)(ws + 16777216);         // [4096][3072] bf16   (24 MB)
  u16* atty = (u16*)(ws + 41943040);         // [4096][1024] bf16   (8 MB)

  prep<<<6144, 256, 0, stream>>>(x, Wqkv, Wproj, xb, wqT, wpT);
  gemm_bt<128, 192, false><<<dim3(32, 16), 256, 0, stream>>>(xb, wqT, (void*)qkv, nullptr, 4096, 3072, 1024);
  attn_fwd<<<dim3(16, 16, 2), 512, 0, stream>>>(qkv, atty);
  gemm_bt<128, 64, true><<<dim3(32, 16), 256, 0, stream>>>(atty, wpT, d_out, bproj, 4096, 1024, 1024);
}

// Round 18
// 103.815 us; speedup vs baseline: 1.0768x; 1.0768x over previous
//
#include <hip/hip_runtime.h>
#include <hip/hip_bf16.h>

typedef unsigned short u16;
typedef unsigned int u32;
typedef u16 u16x4 __attribute__((ext_vector_type(4)));
typedef u16 u16x8 __attribute__((ext_vector_type(8)));
typedef u32 u32x4 __attribute__((ext_vector_type(4)));
typedef __bf16 bf16x8 __attribute__((ext_vector_type(8)));
typedef float f32x4 __attribute__((ext_vector_type(4)));

__device__ __forceinline__ u16 f2bf(float f) {
  union { float f; unsigned u; } v; v.f = f;
  unsigned r = v.u + 0x7fffu + ((v.u >> 16) & 1u);
  return (u16)(r >> 16);
}

__device__ __forceinline__ u16 bf(float f) {
  __bf16 h = (__bf16)f;
  union { __bf16 h; u16 u; } c; c.h = h;
  return c.u;
}

__device__ __forceinline__ u32 pack2(float lo, float hi) {
  return (u32)bf(lo) | ((u32)bf(hi) << 16);
}

__device__ __forceinline__ float fexp2(float x) {
#if __has_builtin(__builtin_amdgcn_exp2f)
  return __builtin_amdgcn_exp2f(x);
#else
  return exp2f(x);
#endif
}

__device__ __forceinline__ float frcp(float x) {
#if __has_builtin(__builtin_amdgcn_rcpf)
  return __builtin_amdgcn_rcpf(x);
#else
  return 1.0f / x;
#endif
}

__device__ __forceinline__ void gload16(const void* g, void* l) {
  __builtin_amdgcn_global_load_lds((const __attribute__((address_space(1))) void*)g,
                                   (__attribute__((address_space(3))) void*)l, 16, 0, 0);
}

// ---- merged prep: x f32->bf16 (blocks 0..2047) + weight transposes (2048..6143)
__global__ __launch_bounds__(256) void prep(
    const float* __restrict__ x, const float* __restrict__ Wqkv,
    const float* __restrict__ Wproj, u16* __restrict__ xb,
    u16* __restrict__ wqT, u16* __restrict__ wpT)
{
  __shared__ float tile[32][33];
  const int bid = blockIdx.x;
  if (bid < 2048) {
    int i = (bid * 256 + threadIdx.x) * 8;
    f32x4 a = *(const f32x4*)(x + i);
    f32x4 b = *(const f32x4*)(x + i + 4);
    u16x8 r;
    r[0] = f2bf(a[0]); r[1] = f2bf(a[1]); r[2] = f2bf(a[2]); r[3] = f2bf(a[3]);
    r[4] = f2bf(b[0]); r[5] = f2bf(b[1]); r[6] = f2bf(b[2]); r[7] = f2bf(b[3]);
    *(u16x8*)(xb + i) = r;
    return;
  }
  int flat = bid - 2048;
  int bx = flat & 127, by = flat >> 7;
  const float* in;
  u16* out;
  int N;
  if (bx < 96) { in = Wqkv; out = wqT; N = 3072; }
  else         { in = Wproj; out = wpT; N = 1024; bx -= 96; }
  const int K = 1024;
  int n0 = bx * 32, k0 = by * 32;
  int tx = threadIdx.x & 31, ty = threadIdx.x >> 5;
  for (int i = 0; i < 32; i += 8)
    tile[ty + i][tx] = in[(long)(k0 + ty + i) * N + n0 + tx];
  __syncthreads();
  for (int i = 0; i < 32; i += 8)
    out[(long)(n0 + ty + i) * K + k0 + tx] = f2bf(tile[tx][ty + i]);
}

// ------------- GEMM: C[M][N] = A[M][K] * Bt[N][K]^T (+bias), BK=64 -------------
template<int BM, int BN, bool F32OUT>
__global__ __launch_bounds__(256) void gemm_bt(
    const u16* __restrict__ A, const u16* __restrict__ Bt,
    void* __restrict__ Cp, const float* __restrict__ bias,
    int M, int N, int K)
{
  constexpr int MR = BM / 32, NR = BN / 32;
  constexpr int RA = BM / 32, RB = BN / 32;
  __shared__ char lds[(BM + BN) * 128];
  char* As = lds;
  char* Bs = lds + BM * 128;
  const int tid = threadIdx.x;
  const int l = tid & 63, w = tid >> 6;
  const int wr = w >> 1, wc = w & 1;
  const int lr = l & 15, q4 = l >> 4;
  const long row0 = (long)blockIdx.x * BM;
  const long col0 = (long)blockIdx.y * BN;

  f32x4 acc[MR][NR] = {};

  const u16* gA[RA];
  int oA[RA];
  for (int i = 0; i < RA; ++i) {
    int cc = i * 256 + tid;
    int r = cc >> 3, c = (cc & 7) ^ (r & 7);
    oA[i] = cc * 16;
    gA[i] = A + (row0 + r) * K + c * 8;
  }
  const u16* gB[RB];
  int oB[RB];
  for (int i = 0; i < RB; ++i) {
    int cc = i * 256 + tid;
    int r = cc >> 3, c = (cc & 7) ^ (r & 7);
    oB[i] = cc * 16;
    gB[i] = Bt + (col0 + r) * K + c * 8;
  }

  for (int k0 = 0; k0 < K; k0 += 64) {
    __syncthreads();
    for (int i = 0; i < RA; ++i) gload16(gA[i] + k0, As + oA[i]);
    for (int i = 0; i < RB; ++i) gload16(gB[i] + k0, Bs + oB[i]);
    __syncthreads();
    for (int kk = 0; kk < 2; ++kk) {
      bf16x8 a[MR], b[NR];
      for (int m = 0; m < MR; ++m) {
        int r = wr * (BM / 2) + m * 16 + lr;
        a[m] = *(const bf16x8*)(As + r * 128 + (((kk * 4 + q4) ^ (r & 7)) << 4));
      }
      for (int n = 0; n < NR; ++n) {
        int r = wc * (BN / 2) + n * 16 + lr;
        b[n] = *(const bf16x8*)(Bs + r * 128 + (((kk * 4 + q4) ^ (r & 7)) << 4));
      }
      for (int m = 0; m < MR; ++m)
        for (int n = 0; n < NR; ++n)
          acc[m][n] = __builtin_amdgcn_mfma_f32_16x16x32_bf16(a[m], b[n], acc[m][n], 0, 0, 0);
    }
  }

  for (int n = 0; n < NR; ++n) {
    int col = (int)col0 + wc * (BN / 2) + n * 16 + lr;
    float bv = 0.f;
    if (F32OUT) bv = bias[col];
    for (int m = 0; m < MR; ++m) {
      for (int reg = 0; reg < 4; ++reg) {
        long row = row0 + wr * (BM / 2) + m * 16 + q4 * 4 + reg;
        float vv = acc[m][n][reg] + bv;
        if (F32OUT) ((float*)Cp)[row * N + col] = vv;
        else        ((u16*)Cp)[row * N + col] = f2bf(vv);
      }
    }
  }
}

// ------------- causal flash attention -------------
// Round-13/15 structure (512 thr, 8 waves; waves 0-3 -> 64-row q-tile ti,
// waves 4-7 -> tile 31-ti; ring-4 K/V, 2-tile pipeline; fixed-reference
// softmax P = exp2(st)) with the row-sum moved to the MFMA pipe:
// ls = mfma(ones, pf, ls) computes the FULL 32-key row sum per instruction
// (k-dim spans all 4 g-groups) -> deletes the psum VALU tree AND the
// epilogue cross-lane reduction.
// V column permutation: key = n*16+g*4+r -> col' = (n>>1)*32+g*8+(n&1)*4+r
#define FXOR(d) (((((d) & 7) ^ (((d) >> 3) & 7))) << 4)

#define VSCAT(vtb, ra, rb)                                                     \
  for (int j = 0; j < 4; ++j) {                                                \
    int d = vd0 + j;                                                           \
    *(u32*)((vtb) + d * 128 + (vcol2 ^ FXOR(d))) = (u32)(ra)[j] | ((u32)(rb)[j] << 16); \
  }

#define COMPUTE_TILE(T)                                                        \
  if (64 * (T) <= wrow + 15) {                                                 \
    char* ks_ = ksmem + ((T) & 3) * 8192;                                      \
    char* vt_ = vtmem + ((T) & 3) * 8192;                                      \
    const int k0_ = 64 * (T);                                                  \
    f32x4 st[4] = {};                                                          \
    __builtin_amdgcn_s_setprio(1);                                             \
    for (int kk = 0; kk < 2; ++kk)                                             \
      for (int n = 0; n < 4; ++n) {                                            \
        int r = n * 16 + lr;                                                   \
        int c = (kk * 4 + g) ^ (r & 7);                                        \
        bf16x8 kf = *(const bf16x8*)(ks_ + r * 128 + (c << 4));                \
        st[n] = __builtin_amdgcn_mfma_f32_16x16x32_bf16(kf, qf[kk], st[n], 0, 0, 0); \
      }                                                                        \
    __builtin_amdgcn_s_setprio(0);                                             \
    if (k0_ + 63 > wrow) {                                                     \
      for (int n = 0; n < 4; ++n)                                              \
        for (int reg = 0; reg < 4; ++reg)                                      \
          if (k0_ + n * 16 + g * 4 + reg > wrow + lr)                          \
            st[n][reg] = -__builtin_inff();                                    \
    }                                                                          \
    u32 pk[4][2];                                                              \
    for (int n = 0; n < 4; ++n) {                                              \
      float p0 = fexp2(st[n][0]), p1 = fexp2(st[n][1]);                        \
      float p2 = fexp2(st[n][2]), p3 = fexp2(st[n][3]);                        \
      pk[n][0] = pack2(p0, p1);                                                \
      pk[n][1] = pack2(p2, p3);                                                \
    }                                                                          \
    __builtin_amdgcn_s_setprio(1);                                             \
    for (int kt = 0; kt < 2; ++kt) {                                           \
      u32x4 pb;                                                                \
      pb[0] = pk[2 * kt][0]; pb[1] = pk[2 * kt][1];                            \
      pb[2] = pk[2 * kt + 1][0]; pb[3] = pk[2 * kt + 1][1];                    \
      bf16x8 pf = *(bf16x8*)&pb;                                               \
      for (int n = 0; n < 4; ++n) {                                            \
        int dd = n * 16 + lr;                                                  \
        bf16x8 vf = *(const bf16x8*)(vt_ + dd * 128 + ((kt * 64 + g * 16) ^ FXOR(dd))); \
        o[n] = __builtin_amdgcn_mfma_f32_16x16x32_bf16(vf, pf, o[n], 0, 0, 0); \
      }                                                                        \
      ls = __builtin_amdgcn_mfma_f32_16x16x32_bf16(ones, pf, ls, 0, 0, 0);     \
    }                                                                          \
    __builtin_amdgcn_s_setprio(0);                                             \
  }

__global__ __launch_bounds__(512) void attn_fwd(
    const u16* __restrict__ qkv, u16* __restrict__ atty)
{
  __shared__ char ksmem[4 * 8192];      // K ring buffer (tile t -> buf t&3)
  __shared__ char vtmem[4 * 8192];      // Vt[d][col'] ring buffer, swizzled
  const int tid = threadIdx.x;
  const int l = tid & 63, w = tid >> 6;
  const int lr = l & 15, g = l >> 4;
  const int h = blockIdx.y;
  const int ti = blockIdx.x;            // pair index 0..15
  const long base = (long)blockIdx.z * 2048;
  // waves 0-3: q-tile ti (rows 64*ti..); waves 4-7: q-tile 31-ti
  const int wrow = (w < 4) ? (ti * 64 + w * 16) : ((31 - ti) * 64 + (w - 4) * 16);

  // Q fragment (B-operand): lane holds Q[q=wrow+lr][k=kk*32+g*8..], pre-scaled
  bf16x8 qf[2];
  for (int kk = 0; kk < 2; ++kk) {
    u16x8 raw = *(const u16x8*)(qkv + (base + wrow + lr) * 3072 + h * 64 + kk * 32 + g * 8);
    u16x8 sc;
    for (int j = 0; j < 8; ++j) {
      union { unsigned u; float f; } c; c.u = ((unsigned)raw[j]) << 16;
      sc[j] = bf(c.f * 0.18033688f);   // 0.125 * log2(e)
    }
    qf[kk] = *(bf16x8*)&sc;
  }

  f32x4 ls = {};                        // MFMA row-sum accumulator
  f32x4 o[4] = {};
  u32x4 onesu = {0x3F803F80u, 0x3F803F80u, 0x3F803F80u, 0x3F803F80u};
  bf16x8 ones = *(bf16x8*)&onesu;

  // K staging: one 16B global_load_lds per thread (512 chunks = 64 rows x 128B)
  const int kr = tid >> 3, kc = (tid & 7) ^ (kr & 7);
  const u16* kg = qkv + (base + kr) * 3072 + 1024 + h * 64 + kc * 8;
  // V staging: all 512 threads; key-pair (2a,2a+1) x 4 d's; u32 writes
  const int va = tid >> 4;              // key-pair index 0..31
  const int vd0 = (tid & 15) * 4;       // d group
  const int vk0 = va * 2;
  const int vn = vk0 >> 4, vgp2 = (vk0 >> 2) & 3, vr = vk0 & 3;
  const int vcol2 = ((vn >> 1) * 32 + vgp2 * 8 + (vn & 1) * 4 + vr) * 2; // byte
  const u16* vgp = qkv + (base + vk0) * 3072 + 2048 + h * 64 + vd0;

  const int nkv = 32 - ti;              // KV range of the hi tile (>= 17)

  // prologue: stage tiles 0 and 1
  {
    u16x4 a0 = *(const u16x4*)(vgp);
    u16x4 b0 = *(const u16x4*)(vgp + 3072);
    u16x4 a1 = *(const u16x4*)(vgp + 196608);
    u16x4 b1 = *(const u16x4*)(vgp + 196608 + 3072);
    gload16(kg, ksmem + tid * 16);
    gload16(kg + 196608, ksmem + 8192 + tid * 16);
    VSCAT(vtmem, a0, b0);
    VSCAT(vtmem + 8192, a1, b1);
  }
  __syncthreads();

  for (int tb = 0; tb < nkv; tb += 2) {
    // issue stages for tiles tb+2, tb+3 (ring bufs (tb+2)&3, (tb+3)&3)
    u16x4 p2a, p2b, p3a, p3b;
    const bool pf2 = (tb + 2) < nkv, pf3 = (tb + 3) < nkv;
    if (pf2) {
      long off = (long)(tb + 2) * 196608;
      p2a = *(const u16x4*)(vgp + off);
      p2b = *(const u16x4*)(vgp + off + 3072);
      gload16(kg + off, ksmem + ((tb + 2) & 3) * 8192 + tid * 16);
    }
    if (pf3) {
      long off = (long)(tb + 3) * 196608;
      p3a = *(const u16x4*)(vgp + off);
      p3b = *(const u16x4*)(vgp + off + 3072);
      gload16(kg + off, ksmem + ((tb + 3) & 3) * 8192 + tid * 16);
    }

    // compute tiles tb, tb+1 (independent) while the stage loads fly
    COMPUTE_TILE(tb);
    if (tb + 1 < nkv) COMPUTE_TILE(tb + 1);

    // publish V(tb+2), V(tb+3); single barrier drains K DMA + orders scatter
    if (pf2) VSCAT(vtmem + ((tb + 2) & 3) * 8192, p2a, p2b);
    if (pf3) VSCAT(vtmem + ((tb + 3) & 3) * 8192, p3a, p3b);
    __syncthreads();
  }

  // epilogue: ls[0] already holds the FULL row sum (MFMA reduced across all
  // key slices); normalize, 8B coalesced stores
  float inv = frcp(ls[0]);
  long row = base + wrow + lr;
  for (int n = 0; n < 4; ++n) {
    u16x4 ov;
    for (int reg = 0; reg < 4; ++reg) ov[reg] = bf(o[n][reg] * inv);
    *(u16x4*)(atty + row * 1024 + h * 64 + n * 16 + g * 4) = ov;
  }
}

extern "C" void kernel_launch(void* const* d_in, const int* in_sizes, int n_in,
                              void* d_out, int out_size, void* d_ws, size_t ws_size,
                              hipStream_t stream) {
  const float* x     = (const float*)d_in[0];
  const float* Wqkv  = (const float*)d_in[1];
  const float* Wproj = (const float*)d_in[2];
  const float* bproj = (const float*)d_in[3];
  char* ws = (char*)d_ws;
  u16* xb   = (u16*)(ws);                    // 4096*1024 bf16      (8 MB)
  u16* wqT  = (u16*)(ws + 8388608);          // [3072][1024] bf16   (6 MB)
  u16* wpT  = (u16*)(ws + 14680064);         // [1024][1024] bf16   (2 MB)
  u16* qkv  = (u16*)(ws + 16777216);         // [4096][3072] bf16   (24 MB)
  u16* atty = (u16*)(ws + 41943040);         // [4096][1024] bf16   (8 MB)

  prep<<<6144, 256, 0, stream>>>(x, Wqkv, Wproj, xb, wqT, wpT);
  gemm_bt<128, 192, false><<<dim3(32, 16), 256, 0, stream>>>(xb, wqT, (void*)qkv, nullptr, 4096, 3072, 1024);
  attn_fwd<<<dim3(16, 16, 2), 512, 0, stream>>>(qkv, atty);
  gemm_bt<128, 64, true><<<dim3(32, 16), 256, 0, stream>>>(atty, wpT, d_out, bproj, 4096, 1024, 1024);
}

// Round 19
// 97.422 us; speedup vs baseline: 1.1474x; 1.0656x over previous
//
#include <hip/hip_runtime.h>
#include <hip/hip_bf16.h>

typedef unsigned short u16;
typedef unsigned int u32;
typedef u16 u16x4 __attribute__((ext_vector_type(4)));
typedef u16 u16x8 __attribute__((ext_vector_type(8)));
typedef u32 u32x4 __attribute__((ext_vector_type(4)));
typedef __bf16 bf16x8 __attribute__((ext_vector_type(8)));
typedef float f32x4 __attribute__((ext_vector_type(4)));

__device__ __forceinline__ u16 f2bf(float f) {
  union { float f; unsigned u; } v; v.f = f;
  unsigned r = v.u + 0x7fffu + ((v.u >> 16) & 1u);
  return (u16)(r >> 16);
}

__device__ __forceinline__ u16 bf(float f) {
  __bf16 h = (__bf16)f;
  union { __bf16 h; u16 u; } c; c.h = h;
  return c.u;
}

__device__ __forceinline__ u32 pack2(float lo, float hi) {
  return (u32)bf(lo) | ((u32)bf(hi) << 16);
}

__device__ __forceinline__ float fexp2(float x) {
#if __has_builtin(__builtin_amdgcn_exp2f)
  return __builtin_amdgcn_exp2f(x);
#else
  return exp2f(x);
#endif
}

__device__ __forceinline__ float frcp(float x) {
#if __has_builtin(__builtin_amdgcn_rcpf)
  return __builtin_amdgcn_rcpf(x);
#else
  return 1.0f / x;
#endif
}

__device__ __forceinline__ void gload16(const void* g, void* l) {
  __builtin_amdgcn_global_load_lds((const __attribute__((address_space(1))) void*)g,
                                   (__attribute__((address_space(3))) void*)l, 16, 0, 0);
}

// ---- merged prep: x f32->bf16 (blocks 0..2047) + weight transposes (2048..6143)
__global__ __launch_bounds__(256) void prep(
    const float* __restrict__ x, const float* __restrict__ Wqkv,
    const float* __restrict__ Wproj, u16* __restrict__ xb,
    u16* __restrict__ wqT, u16* __restrict__ wpT)
{
  __shared__ float tile[32][33];
  const int bid = blockIdx.x;
  if (bid < 2048) {
    int i = (bid * 256 + threadIdx.x) * 8;
    f32x4 a = *(const f32x4*)(x + i);
    f32x4 b = *(const f32x4*)(x + i + 4);
    u16x8 r;
    r[0] = f2bf(a[0]); r[1] = f2bf(a[1]); r[2] = f2bf(a[2]); r[3] = f2bf(a[3]);
    r[4] = f2bf(b[0]); r[5] = f2bf(b[1]); r[6] = f2bf(b[2]); r[7] = f2bf(b[3]);
    *(u16x8*)(xb + i) = r;
    return;
  }
  int flat = bid - 2048;
  int bx = flat & 127, by = flat >> 7;
  const float* in;
  u16* out;
  int N;
  if (bx < 96) { in = Wqkv; out = wqT; N = 3072; }
  else         { in = Wproj; out = wpT; N = 1024; bx -= 96; }
  const int K = 1024;
  int n0 = bx * 32, k0 = by * 32;
  int tx = threadIdx.x & 31, ty = threadIdx.x >> 5;
  for (int i = 0; i < 32; i += 8)
    tile[ty + i][tx] = in[(long)(k0 + ty + i) * N + n0 + tx];
  __syncthreads();
  for (int i = 0; i < 32; i += 8)
    out[(long)(n0 + ty + i) * K + k0 + tx] = f2bf(tile[tx][ty + i]);
}

// ------------- GEMM: C[M][N] = A[M][K] * Bt[N][K]^T (+bias), BK=64 -------------
template<int BM, int BN, bool F32OUT>
__global__ __launch_bounds__(256) void gemm_bt(
    const u16* __restrict__ A, const u16* __restrict__ Bt,
    void* __restrict__ Cp, const float* __restrict__ bias,
    int M, int N, int K)
{
  constexpr int MR = BM / 32, NR = BN / 32;
  constexpr int RA = BM / 32, RB = BN / 32;
  __shared__ char lds[(BM + BN) * 128];
  char* As = lds;
  char* Bs = lds + BM * 128;
  const int tid = threadIdx.x;
  const int l = tid & 63, w = tid >> 6;
  const int wr = w >> 1, wc = w & 1;
  const int lr = l & 15, q4 = l >> 4;
  const long row0 = (long)blockIdx.x * BM;
  const long col0 = (long)blockIdx.y * BN;

  f32x4 acc[MR][NR] = {};

  const u16* gA[RA];
  int oA[RA];
  for (int i = 0; i < RA; ++i) {
    int cc = i * 256 + tid;
    int r = cc >> 3, c = (cc & 7) ^ (r & 7);
    oA[i] = cc * 16;
    gA[i] = A + (row0 + r) * K + c * 8;
  }
  const u16* gB[RB];
  int oB[RB];
  for (int i = 0; i < RB; ++i) {
    int cc = i * 256 + tid;
    int r = cc >> 3, c = (cc & 7) ^ (r & 7);
    oB[i] = cc * 16;
    gB[i] = Bt + (col0 + r) * K + c * 8;
  }

  for (int k0 = 0; k0 < K; k0 += 64) {
    __syncthreads();
    for (int i = 0; i < RA; ++i) gload16(gA[i] + k0, As + oA[i]);
    for (int i = 0; i < RB; ++i) gload16(gB[i] + k0, Bs + oB[i]);
    __syncthreads();
    for (int kk = 0; kk < 2; ++kk) {
      bf16x8 a[MR], b[NR];
      for (int m = 0; m < MR; ++m) {
        int r = wr * (BM / 2) + m * 16 + lr;
        a[m] = *(const bf16x8*)(As + r * 128 + (((kk * 4 + q4) ^ (r & 7)) << 4));
      }
      for (int n = 0; n < NR; ++n) {
        int r = wc * (BN / 2) + n * 16 + lr;
        b[n] = *(const bf16x8*)(Bs + r * 128 + (((kk * 4 + q4) ^ (r & 7)) << 4));
      }
      for (int m = 0; m < MR; ++m)
        for (int n = 0; n < NR; ++n)
          acc[m][n] = __builtin_amdgcn_mfma_f32_16x16x32_bf16(a[m], b[n], acc[m][n], 0, 0, 0);
    }
  }

  for (int n = 0; n < NR; ++n) {
    int col = (int)col0 + wc * (BN / 2) + n * 16 + lr;
    float bv = 0.f;
    if (F32OUT) bv = bias[col];
    for (int m = 0; m < MR; ++m) {
      for (int reg = 0; reg < 4; ++reg) {
        long row = row0 + wr * (BM / 2) + m * 16 + q4 * 4 + reg;
        float vv = acc[m][n][reg] + bv;
        if (F32OUT) ((float*)Cp)[row * N + col] = vv;
        else        ((u16*)Cp)[row * N + col] = f2bf(vv);
      }
    }
  }
}

// ------------- causal flash attention -------------
// Round-17 structure (512 thr, 8 waves; waves 0-3 -> 64-row q-tile ti,
// waves 4-7 -> tile 31-ti; ring-4 K/V, 2-tile pipeline; fixed-reference
// softmax; ls row-sum on the MFMA pipe) with DURATION-COMPLEMENTARY grid
// mapping: grid (32,16), x = h + 16z, y -> ti via perm[y] = y<8 ? y : 23-y
// (perm[y+8] = 15-perm[y]). A CU's two resident blocks (ids k, k+256 under
// any mod-256 round-robin, incl. XCD round-robin) then get ti = a and 15-a
// -> per-CU work (32-a)+(17+a) = 49 iterations, uniform across all CUs.
// V column permutation: key = n*16+g*4+r -> col' = (n>>1)*32+g*8+(n&1)*4+r
#define FXOR(d) (((((d) & 7) ^ (((d) >> 3) & 7))) << 4)

#define VSCAT(vtb, ra, rb)                                                     \
  for (int j = 0; j < 4; ++j) {                                                \
    int d = vd0 + j;                                                           \
    *(u32*)((vtb) + d * 128 + (vcol2 ^ FXOR(d))) = (u32)(ra)[j] | ((u32)(rb)[j] << 16); \
  }

#define COMPUTE_TILE(T)                                                        \
  if (64 * (T) <= wrow + 15) {                                                 \
    char* ks_ = ksmem + ((T) & 3) * 8192;                                      \
    char* vt_ = vtmem + ((T) & 3) * 8192;                                      \
    const int k0_ = 64 * (T);                                                  \
    f32x4 st[4] = {};                                                          \
    __builtin_amdgcn_s_setprio(1);                                             \
    for (int kk = 0; kk < 2; ++kk)                                             \
      for (int n = 0; n < 4; ++n) {                                            \
        int r = n * 16 + lr;                                                   \
        int c = (kk * 4 + g) ^ (r & 7);                                        \
        bf16x8 kf = *(const bf16x8*)(ks_ + r * 128 + (c << 4));                \
        st[n] = __builtin_amdgcn_mfma_f32_16x16x32_bf16(kf, qf[kk], st[n], 0, 0, 0); \
      }                                                                        \
    __builtin_amdgcn_s_setprio(0);                                             \
    if (k0_ + 63 > wrow) {                                                     \
      for (int n = 0; n < 4; ++n)                                              \
        for (int reg = 0; reg < 4; ++reg)                                      \
          if (k0_ + n * 16 + g * 4 + reg > wrow + lr)                          \
            st[n][reg] = -__builtin_inff();                                    \
    }                                                                          \
    u32 pk[4][2];                                                              \
    for (int n = 0; n < 4; ++n) {                                              \
      float p0 = fexp2(st[n][0]), p1 = fexp2(st[n][1]);                        \
      float p2 = fexp2(st[n][2]), p3 = fexp2(st[n][3]);                        \
      pk[n][0] = pack2(p0, p1);                                                \
      pk[n][1] = pack2(p2, p3);                                                \
    }                                                                          \
    __builtin_amdgcn_s_setprio(1);                                             \
    for (int kt = 0; kt < 2; ++kt) {                                           \
      u32x4 pb;                                                                \
      pb[0] = pk[2 * kt][0]; pb[1] = pk[2 * kt][1];                            \
      pb[2] = pk[2 * kt + 1][0]; pb[3] = pk[2 * kt + 1][1];                    \
      bf16x8 pf = *(bf16x8*)&pb;                                               \
      for (int n = 0; n < 4; ++n) {                                            \
        int dd = n * 16 + lr;                                                  \
        bf16x8 vf = *(const bf16x8*)(vt_ + dd * 128 + ((kt * 64 + g * 16) ^ FXOR(dd))); \
        o[n] = __builtin_amdgcn_mfma_f32_16x16x32_bf16(vf, pf, o[n], 0, 0, 0); \
      }                                                                        \
      ls = __builtin_amdgcn_mfma_f32_16x16x32_bf16(ones, pf, ls, 0, 0, 0);     \
    }                                                                          \
    __builtin_amdgcn_s_setprio(0);                                             \
  }

__global__ __launch_bounds__(512) void attn_fwd(
    const u16* __restrict__ qkv, u16* __restrict__ atty)
{
  __shared__ char ksmem[4 * 8192];      // K ring buffer (tile t -> buf t&3)
  __shared__ char vtmem[4 * 8192];      // Vt[d][col'] ring buffer, swizzled
  const int tid = threadIdx.x;
  const int l = tid & 63, w = tid >> 6;
  const int lr = l & 15, g = l >> 4;
  const int xh = blockIdx.x;            // x = h + 16*z
  const int h = xh & 15;
  const long base = (long)(xh >> 4) * 2048;
  const int y = blockIdx.y;             // y -> ti, self-complementary perm
  const int ti = (y < 8) ? y : (23 - y);
  // waves 0-3: q-tile ti (rows 64*ti..); waves 4-7: q-tile 31-ti
  const int wrow = (w < 4) ? (ti * 64 + w * 16) : ((31 - ti) * 64 + (w - 4) * 16);

  // Q fragment (B-operand): lane holds Q[q=wrow+lr][k=kk*32+g*8..], pre-scaled
  bf16x8 qf[2];
  for (int kk = 0; kk < 2; ++kk) {
    u16x8 raw = *(const u16x8*)(qkv + (base + wrow + lr) * 3072 + h * 64 + kk * 32 + g * 8);
    u16x8 sc;
    for (int j = 0; j < 8; ++j) {
      union { unsigned u; float f; } c; c.u = ((unsigned)raw[j]) << 16;
      sc[j] = bf(c.f * 0.18033688f);   // 0.125 * log2(e)
    }
    qf[kk] = *(bf16x8*)&sc;
  }

  f32x4 ls = {};                        // MFMA row-sum accumulator
  f32x4 o[4] = {};
  u32x4 onesu = {0x3F803F80u, 0x3F803F80u, 0x3F803F80u, 0x3F803F80u};
  bf16x8 ones = *(bf16x8*)&onesu;

  // K staging: one 16B global_load_lds per thread (512 chunks = 64 rows x 128B)
  const int kr = tid >> 3, kc = (tid & 7) ^ (kr & 7);
  const u16* kg = qkv + (base + kr) * 3072 + 1024 + h * 64 + kc * 8;
  // V staging: all 512 threads; key-pair (2a,2a+1) x 4 d's; u32 writes
  const int va = tid >> 4;              // key-pair index 0..31
  const int vd0 = (tid & 15) * 4;       // d group
  const int vk0 = va * 2;
  const int vn = vk0 >> 4, vgp2 = (vk0 >> 2) & 3, vr = vk0 & 3;
  const int vcol2 = ((vn >> 1) * 32 + vgp2 * 8 + (vn & 1) * 4 + vr) * 2; // byte
  const u16* vgp = qkv + (base + vk0) * 3072 + 2048 + h * 64 + vd0;

  const int nkv = 32 - ti;              // KV range of the hi tile (>= 17)

  // prologue: stage tiles 0 and 1
  {
    u16x4 a0 = *(const u16x4*)(vgp);
    u16x4 b0 = *(const u16x4*)(vgp + 3072);
    u16x4 a1 = *(const u16x4*)(vgp + 196608);
    u16x4 b1 = *(const u16x4*)(vgp + 196608 + 3072);
    gload16(kg, ksmem + tid * 16);
    gload16(kg + 196608, ksmem + 8192 + tid * 16);
    VSCAT(vtmem, a0, b0);
    VSCAT(vtmem + 8192, a1, b1);
  }
  __syncthreads();

  for (int tb = 0; tb < nkv; tb += 2) {
    // issue stages for tiles tb+2, tb+3 (ring bufs (tb+2)&3, (tb+3)&3)
    u16x4 p2a, p2b, p3a, p3b;
    const bool pf2 = (tb + 2) < nkv, pf3 = (tb + 3) < nkv;
    if (pf2) {
      long off = (long)(tb + 2) * 196608;
      p2a = *(const u16x4*)(vgp + off);
      p2b = *(const u16x4*)(vgp + off + 3072);
      gload16(kg + off, ksmem + ((tb + 2) & 3) * 8192 + tid * 16);
    }
    if (pf3) {
      long off = (long)(tb + 3) * 196608;
      p3a = *(const u16x4*)(vgp + off);
      p3b = *(const u16x4*)(vgp + off + 3072);
      gload16(kg + off, ksmem + ((tb + 3) & 3) * 8192 + tid * 16);
    }

    // compute tiles tb, tb+1 (independent) while the stage loads fly
    COMPUTE_TILE(tb);
    if (tb + 1 < nkv) COMPUTE_TILE(tb + 1);

    // publish V(tb+2), V(tb+3); single barrier drains K DMA + orders scatter
    if (pf2) VSCAT(vtmem + ((tb + 2) & 3) * 8192, p2a, p2b);
    if (pf3) VSCAT(vtmem + ((tb + 3) & 3) * 8192, p3a, p3b);
    __syncthreads();
  }

  // epilogue: ls[0] already holds the FULL row sum (MFMA reduced across all
  // key slices); normalize, 8B coalesced stores
  float inv = frcp(ls[0]);
  long row = base + wrow + lr;
  for (int n = 0; n < 4; ++n) {
    u16x4 ov;
    for (int reg = 0; reg < 4; ++reg) ov[reg] = bf(o[n][reg] * inv);
    *(u16x4*)(atty + row * 1024 + h * 64 + n * 16 + g * 4) = ov;
  }
}

extern "C" void kernel_launch(void* const* d_in, const int* in_sizes, int n_in,
                              void* d_out, int out_size, void* d_ws, size_t ws_size,
                              hipStream_t stream) {
  const float* x     = (const float*)d_in[0];
  const float* Wqkv  = (const float*)d_in[1];
  const float* Wproj = (const float*)d_in[2];
  const float* bproj = (const float*)d_in[3];
  char* ws = (char*)d_ws;
  u16* xb   = (u16*)(ws);                    // 4096*1024 bf16      (8 MB)
  u16* wqT  = (u16*)(ws + 8388608);          // [3072][1024] bf16   (6 MB)
  u16* wpT  = (u16*)(ws + 14680064);         // [1024][1024] bf16   (2 MB)
  u16* qkv  = (u16*)(ws + 16777216);         // [4096][3072] bf16   (24 MB)
  u16* atty = (u16*)(ws + 41943040);         // [4096][1024] bf16   (8 MB)

  prep<<<6144, 256, 0, stream>>>(x, Wqkv, Wproj, xb, wqT, wpT);
  gemm_bt<128, 192, false><<<dim3(32, 16), 256, 0, stream>>>(xb, wqT, (void*)qkv, nullptr, 4096, 3072, 1024);
  attn_fwd<<<dim3(32, 16), 512, 0, stream>>>(qkv, atty);
  gemm_bt<128, 64, true><<<dim3(32, 16), 256, 0, stream>>>(atty, wpT, d_out, bproj, 4096, 1024, 1024);
}

// Round 20
// 95.226 us; speedup vs baseline: 1.1739x; 1.0231x over previous
//
#include <hip/hip_runtime.h>
#include <hip/hip_bf16.h>

typedef unsigned short u16;
typedef unsigned int u32;
typedef u16 u16x4 __attribute__((ext_vector_type(4)));
typedef u16 u16x8 __attribute__((ext_vector_type(8)));
typedef u32 u32x4 __attribute__((ext_vector_type(4)));
typedef __bf16 bf16x8 __attribute__((ext_vector_type(8)));
typedef float f32x4 __attribute__((ext_vector_type(4)));

__device__ __forceinline__ u16 f2bf(float f) {
  union { float f; unsigned u; } v; v.f = f;
  unsigned r = v.u + 0x7fffu + ((v.u >> 16) & 1u);
  return (u16)(r >> 16);
}

__device__ __forceinline__ u16 bf(float f) {
  __bf16 h = (__bf16)f;
  union { __bf16 h; u16 u; } c; c.h = h;
  return c.u;
}

__device__ __forceinline__ u32 pack2(float lo, float hi) {
  return (u32)bf(lo) | ((u32)bf(hi) << 16);
}

__device__ __forceinline__ float fexp2(float x) {
#if __has_builtin(__builtin_amdgcn_exp2f)
  return __builtin_amdgcn_exp2f(x);
#else
  return exp2f(x);
#endif
}

__device__ __forceinline__ float frcp(float x) {
#if __has_builtin(__builtin_amdgcn_rcpf)
  return __builtin_amdgcn_rcpf(x);
#else
  return 1.0f / x;
#endif
}

__device__ __forceinline__ void gload16(const void* g, void* l) {
  __builtin_amdgcn_global_load_lds((const __attribute__((address_space(1))) void*)g,
                                   (__attribute__((address_space(3))) void*)l, 16, 0, 0);
}

// ---- merged prep: x f32->bf16 (blocks 0..2047) + weight transposes (2048..6143)
__global__ __launch_bounds__(256) void prep(
    const float* __restrict__ x, const float* __restrict__ Wqkv,
    const float* __restrict__ Wproj, u16* __restrict__ xb,
    u16* __restrict__ wqT, u16* __restrict__ wpT)
{
  __shared__ float tile[32][33];
  const int bid = blockIdx.x;
  if (bid < 2048) {
    int i = (bid * 256 + threadIdx.x) * 8;
    f32x4 a = *(const f32x4*)(x + i);
    f32x4 b = *(const f32x4*)(x + i + 4);
    u16x8 r;
    r[0] = f2bf(a[0]); r[1] = f2bf(a[1]); r[2] = f2bf(a[2]); r[3] = f2bf(a[3]);
    r[4] = f2bf(b[0]); r[5] = f2bf(b[1]); r[6] = f2bf(b[2]); r[7] = f2bf(b[3]);
    *(u16x8*)(xb + i) = r;
    return;
  }
  int flat = bid - 2048;
  int bx = flat & 127, by = flat >> 7;
  const float* in;
  u16* out;
  int N;
  if (bx < 96) { in = Wqkv; out = wqT; N = 3072; }
  else         { in = Wproj; out = wpT; N = 1024; bx -= 96; }
  const int K = 1024;
  int n0 = bx * 32, k0 = by * 32;
  int tx = threadIdx.x & 31, ty = threadIdx.x >> 5;
  for (int i = 0; i < 32; i += 8)
    tile[ty + i][tx] = in[(long)(k0 + ty + i) * N + n0 + tx];
  __syncthreads();
  for (int i = 0; i < 32; i += 8)
    out[(long)(n0 + ty + i) * K + k0 + tx] = f2bf(tile[tx][ty + i]);
}

// ------------- GEMM: C[M][N] = A[M][K] * Bt[N][K]^T (+bias), BK=64 -------------
template<int BM, int BN, bool F32OUT>
__global__ __launch_bounds__(256) void gemm_bt(
    const u16* __restrict__ A, const u16* __restrict__ Bt,
    void* __restrict__ Cp, const float* __restrict__ bias,
    int M, int N, int K)
{
  constexpr int MR = BM / 32, NR = BN / 32;
  constexpr int RA = BM / 32, RB = BN / 32;
  __shared__ char lds[(BM + BN) * 128];
  char* As = lds;
  char* Bs = lds + BM * 128;
  const int tid = threadIdx.x;
  const int l = tid & 63, w = tid >> 6;
  const int wr = w >> 1, wc = w & 1;
  const int lr = l & 15, q4 = l >> 4;
  const long row0 = (long)blockIdx.x * BM;
  const long col0 = (long)blockIdx.y * BN;

  f32x4 acc[MR][NR] = {};

  const u16* gA[RA];
  int oA[RA];
  for (int i = 0; i < RA; ++i) {
    int cc = i * 256 + tid;
    int r = cc >> 3, c = (cc & 7) ^ (r & 7);
    oA[i] = cc * 16;
    gA[i] = A + (row0 + r) * K + c * 8;
  }
  const u16* gB[RB];
  int oB[RB];
  for (int i = 0; i < RB; ++i) {
    int cc = i * 256 + tid;
    int r = cc >> 3, c = (cc & 7) ^ (r & 7);
    oB[i] = cc * 16;
    gB[i] = Bt + (col0 + r) * K + c * 8;
  }

  for (int k0 = 0; k0 < K; k0 += 64) {
    __syncthreads();
    for (int i = 0; i < RA; ++i) gload16(gA[i] + k0, As + oA[i]);
    for (int i = 0; i < RB; ++i) gload16(gB[i] + k0, Bs + oB[i]);
    __syncthreads();
    for (int kk = 0; kk < 2; ++kk) {
      bf16x8 a[MR], b[NR];
      for (int m = 0; m < MR; ++m) {
        int r = wr * (BM / 2) + m * 16 + lr;
        a[m] = *(const bf16x8*)(As + r * 128 + (((kk * 4 + q4) ^ (r & 7)) << 4));
      }
      for (int n = 0; n < NR; ++n) {
        int r = wc * (BN / 2) + n * 16 + lr;
        b[n] = *(const bf16x8*)(Bs + r * 128 + (((kk * 4 + q4) ^ (r & 7)) << 4));
      }
      for (int m = 0; m < MR; ++m)
        for (int n = 0; n < NR; ++n)
          acc[m][n] = __builtin_amdgcn_mfma_f32_16x16x32_bf16(a[m], b[n], acc[m][n], 0, 0, 0);
    }
  }

  for (int n = 0; n < NR; ++n) {
    int col = (int)col0 + wc * (BN / 2) + n * 16 + lr;
    float bv = 0.f;
    if (F32OUT) bv = bias[col];
    for (int m = 0; m < MR; ++m) {
      for (int reg = 0; reg < 4; ++reg) {
        long row = row0 + wr * (BM / 2) + m * 16 + q4 * 4 + reg;
        float vv = acc[m][n][reg] + bv;
        if (F32OUT) ((float*)Cp)[row * N + col] = vv;
        else        ((u16*)Cp)[row * N + col] = f2bf(vv);
      }
    }
  }
}

// ------------- causal flash attention -------------
// Round-18 structure (512 thr, 8 waves; waves 0-3 -> 64-row q-tile ti,
// waves 4-7 -> tile 31-ti; fixed-reference softmax; ls row-sum on MFMA pipe;
// duration-complementary grid) with RING-3 LDS (48 KB -> 3 blocks/CU,
// 24 waves): 1-tile body, depth-2 prefetch (stage t+2 into slot (t+2)%3
// while computing slot t%3; slots t, t+1 live = exactly 3). Rotating slot
// POINTERS (uniform scalars; no runtime-indexed arrays).
// V column permutation: key = n*16+g*4+r -> col' = (n>>1)*32+g*8+(n&1)*4+r
#define FXOR(d) (((((d) & 7) ^ (((d) >> 3) & 7))) << 4)

#define VSCAT(vtb, ra, rb)                                                     \
  for (int j = 0; j < 4; ++j) {                                                \
    int d = vd0 + j;                                                           \
    *(u32*)((vtb) + d * 128 + (vcol2 ^ FXOR(d))) = (u32)(ra)[j] | ((u32)(rb)[j] << 16); \
  }

#define COMPUTE_TILE(T, KS, VT)                                                \
  if (64 * (T) <= wrow + 15) {                                                 \
    const int k0_ = 64 * (T);                                                  \
    f32x4 st[4] = {};                                                          \
    __builtin_amdgcn_s_setprio(1);                                             \
    for (int kk = 0; kk < 2; ++kk)                                             \
      for (int n = 0; n < 4; ++n) {                                            \
        int r = n * 16 + lr;                                                   \
        int c = (kk * 4 + g) ^ (r & 7);                                        \
        bf16x8 kf = *(const bf16x8*)((KS) + r * 128 + (c << 4));               \
        st[n] = __builtin_amdgcn_mfma_f32_16x16x32_bf16(kf, qf[kk], st[n], 0, 0, 0); \
      }                                                                        \
    __builtin_amdgcn_s_setprio(0);                                             \
    if (k0_ + 63 > wrow) {                                                     \
      for (int n = 0; n < 4; ++n)                                              \
        for (int reg = 0; reg < 4; ++reg)                                      \
          if (k0_ + n * 16 + g * 4 + reg > wrow + lr)                          \
            st[n][reg] = -__builtin_inff();                                    \
    }                                                                          \
    u32 pk[4][2];                                                              \
    for (int n = 0; n < 4; ++n) {                                              \
      float p0 = fexp2(st[n][0]), p1 = fexp2(st[n][1]);                        \
      float p2 = fexp2(st[n][2]), p3 = fexp2(st[n][3]);                        \
      pk[n][0] = pack2(p0, p1);                                                \
      pk[n][1] = pack2(p2, p3);                                                \
    }                                                                          \
    __builtin_amdgcn_s_setprio(1);                                             \
    for (int kt = 0; kt < 2; ++kt) {                                           \
      u32x4 pb;                                                                \
      pb[0] = pk[2 * kt][0]; pb[1] = pk[2 * kt][1];                            \
      pb[2] = pk[2 * kt + 1][0]; pb[3] = pk[2 * kt + 1][1];                    \
      bf16x8 pf = *(bf16x8*)&pb;                                               \
      for (int n = 0; n < 4; ++n) {                                            \
        int dd = n * 16 + lr;                                                  \
        bf16x8 vf = *(const bf16x8*)((VT) + dd * 128 + ((kt * 64 + g * 16) ^ FXOR(dd))); \
        o[n] = __builtin_amdgcn_mfma_f32_16x16x32_bf16(vf, pf, o[n], 0, 0, 0); \
      }                                                                        \
      ls = __builtin_amdgcn_mfma_f32_16x16x32_bf16(ones, pf, ls, 0, 0, 0);     \
    }                                                                          \
    __builtin_amdgcn_s_setprio(0);                                             \
  }

__global__ __launch_bounds__(512) void attn_fwd(
    const u16* __restrict__ qkv, u16* __restrict__ atty)
{
  __shared__ char ksmem[3 * 8192];      // K ring (3 slots)
  __shared__ char vtmem[3 * 8192];      // Vt[d][col'] ring (3 slots), swizzled
  const int tid = threadIdx.x;
  const int l = tid & 63, w = tid >> 6;
  const int lr = l & 15, g = l >> 4;
  const int xh = blockIdx.x;            // x = h + 16*z
  const int h = xh & 15;
  const long base = (long)(xh >> 4) * 2048;
  const int y = blockIdx.y;             // y -> ti, self-complementary perm
  const int ti = (y < 8) ? y : (23 - y);
  // waves 0-3: q-tile ti (rows 64*ti..); waves 4-7: q-tile 31-ti
  const int wrow = (w < 4) ? (ti * 64 + w * 16) : ((31 - ti) * 64 + (w - 4) * 16);

  // Q fragment (B-operand): lane holds Q[q=wrow+lr][k=kk*32+g*8..], pre-scaled
  bf16x8 qf[2];
  for (int kk = 0; kk < 2; ++kk) {
    u16x8 raw = *(const u16x8*)(qkv + (base + wrow + lr) * 3072 + h * 64 + kk * 32 + g * 8);
    u16x8 sc;
    for (int j = 0; j < 8; ++j) {
      union { unsigned u; float f; } c; c.u = ((unsigned)raw[j]) << 16;
      sc[j] = bf(c.f * 0.18033688f);   // 0.125 * log2(e)
    }
    qf[kk] = *(bf16x8*)&sc;
  }

  f32x4 ls = {};                        // MFMA row-sum accumulator
  f32x4 o[4] = {};
  u32x4 onesu = {0x3F803F80u, 0x3F803F80u, 0x3F803F80u, 0x3F803F80u};
  bf16x8 ones = *(bf16x8*)&onesu;

  // K staging: one 16B global_load_lds per thread (512 chunks = 64 rows x 128B)
  const int kr = tid >> 3, kc = (tid & 7) ^ (kr & 7);
  const u16* kg = qkv + (base + kr) * 3072 + 1024 + h * 64 + kc * 8;
  // V staging: all 512 threads; key-pair (2a,2a+1) x 4 d's; u32 writes
  const int va = tid >> 4;              // key-pair index 0..31
  const int vd0 = (tid & 15) * 4;       // d group
  const int vk0 = va * 2;
  const int vn = vk0 >> 4, vgp2 = (vk0 >> 2) & 3, vr = vk0 & 3;
  const int vcol2 = ((vn >> 1) * 32 + vgp2 * 8 + (vn & 1) * 4 + vr) * 2; // byte
  const u16* vgp = qkv + (base + vk0) * 3072 + 2048 + h * 64 + vd0;

  const int nkv = 32 - ti;              // KV range of the hi tile (>= 17)

  // prologue: stage tiles 0 and 1 into slots 0 and 1
  {
    u16x4 a0 = *(const u16x4*)(vgp);
    u16x4 b0 = *(const u16x4*)(vgp + 3072);
    u16x4 a1 = *(const u16x4*)(vgp + 196608);
    u16x4 b1 = *(const u16x4*)(vgp + 196608 + 3072);
    gload16(kg, ksmem + tid * 16);
    gload16(kg + 196608, ksmem + 8192 + tid * 16);
    VSCAT(vtmem, a0, b0);
    VSCAT(vtmem + 8192, a1, b1);
  }
  __syncthreads();

  // rotating slot pointers: kA/vA = tile t, kB/vB = t+1, kC/vC = t+2 (staging)
  char* kA = ksmem;         char* vA = vtmem;
  char* kB = ksmem + 8192;  char* vB = vtmem + 8192;
  char* kC = ksmem + 16384; char* vC = vtmem + 16384;

  for (int t = 0; t < nkv; ++t) {
    u16x4 pva, pvb;
    const bool pf = (t + 2) < nkv;
    if (pf) {
      long off = (long)(t + 2) * 196608;
      pva = *(const u16x4*)(vgp + off);
      pvb = *(const u16x4*)(vgp + off + 3072);
      gload16(kg + off, kC + tid * 16);
    }

    COMPUTE_TILE(t, kA, vA);

    if (pf) VSCAT(vC, pva, pvb);
    __syncthreads();                    // drains K DMA + publishes V(t+2)
    char* tk = kA; kA = kB; kB = kC; kC = tk;
    char* tv = vA; vA = vB; vB = vC; vC = tv;
  }

  // epilogue: ls[0] holds the FULL row sum; normalize, 8B coalesced stores
  float inv = frcp(ls[0]);
  long row = base + wrow + lr;
  for (int n = 0; n < 4; ++n) {
    u16x4 ov;
    for (int reg = 0; reg < 4; ++reg) ov[reg] = bf(o[n][reg] * inv);
    *(u16x4*)(atty + row * 1024 + h * 64 + n * 16 + g * 4) = ov;
  }
}

extern "C" void kernel_launch(void* const* d_in, const int* in_sizes, int n_in,
                              void* d_out, int out_size, void* d_ws, size_t ws_size,
                              hipStream_t stream) {
  const float* x     = (const float*)d_in[0];
  const float* Wqkv  = (const float*)d_in[1];
  const float* Wproj = (const float*)d_in[2];
  const float* bproj = (const float*)d_in[3];
  char* ws = (char*)d_ws;
  u16* xb   = (u16*)(ws);                    // 4096*1024 bf16      (8 MB)
  u16* wqT  = (u16*)(ws + 8388608);          // [3072][1024] bf16   (6 MB)
  u16* wpT  = (u16*)(ws + 14680064);         // [1024][1024] bf16   (2 MB)
  u16* qkv  = (u16*)(ws + 16777216);         // [4096][3072] bf16   (24 MB)
  u16* atty = (u16*)(ws + 41943040);         // [4096][1024] bf16   (8 MB)

  prep<<<6144, 256, 0, stream>>>(x, Wqkv, Wproj, xb, wqT, wpT);
  gemm_bt<128, 192, false><<<dim3(32, 16), 256, 0, stream>>>(xb, wqT, (void*)qkv, nullptr, 4096, 3072, 1024);
  attn_fwd<<<dim3(32, 16), 512, 0, stream>>>(qkv, atty);
  gemm_bt<128, 64, true><<<dim3(32, 16), 256, 0, stream>>>(atty, wpT, d_out, bproj, 4096, 1024, 1024);
}